// Round 1
// baseline (163.636 us; speedup 1.0000x reference)
//
#include <hip/hip_runtime.h>
#include <math.h>

#define GRID_N 5
#define LOG2E 1.4426950408889634f

// w[o][i][g] -> wt[i][g][o]  (coalesced main-loop loads, lane = o)
__global__ void prep_w(const float* __restrict__ w, float* __restrict__ wt, int O, int I) {
    int idx = blockIdx.x * 256 + threadIdx.x;
    int total = O * I * GRID_N;
    if (idx >= total) return;
    int o = idx / (I * GRID_N);
    int rem = idx % (I * GRID_N);   // i*5 + g
    wt[rem * O + o] = w[idx];
}

// s[o][i] -> st[i][o] = -s*log2(e)   (so weight = exp2(st * |d|))
__global__ void prep_s(const float* __restrict__ s, float* __restrict__ st, int O, int I) {
    int idx = blockIdx.x * 256 + threadIdx.x;
    if (idx >= O * I) return;
    int o = idx / I, i = idx % I;
    st[i * O + o] = -s[idx] * LOG2E;
}

// One KAN layer: out[b,o] = act( sum_i sum_g wt[i][g][o] * exp2(st[i][o]*|tanh(x[b,i])-g_g|) )
// ACT: 0 = relu, 1 = sigmoid
template<int IN, int OUT, int ACT, int BT>
__global__ __launch_bounds__(256) void kan_layer(
    const float* __restrict__ x,     // [B][IN] (pre-tanh)
    const float* __restrict__ wt,    // [IN][5][OUT]
    const float* __restrict__ st,    // [IN][OUT]
    float* __restrict__ out)         // [B][OUT]
{
    constexpr int WB  = 256 / OUT;   // b-groups among threads
    constexpr int BPT = BT / WB;     // b rows per thread
    __shared__ float xn[BT][IN];

    const int tid = threadIdx.x;
    const int b0  = blockIdx.x * BT;

    // stage input tile with fused tanh (NaN-safe: 1 - 2/(e^{2x}+1))
    for (int e = tid; e < BT * IN; e += 256) {
        int bb = e / IN, ii = e % IN;
        float v = x[(b0 + bb) * IN + ii];
        float t = __builtin_amdgcn_exp2f(2.0f * LOG2E * v);
        xn[bb][ii] = 1.0f - 2.0f / (t + 1.0f);
    }
    __syncthreads();

    const int o  = tid % OUT;
    const int bg = tid / OUT;

    float acc[BPT];
#pragma unroll
    for (int j = 0; j < BPT; j++) acc[j] = 0.0f;

    for (int i = 0; i < IN; i++) {
        float K  = st[i * OUT + o];
        float w0 = wt[(i * GRID_N + 0) * OUT + o];
        float w1 = wt[(i * GRID_N + 1) * OUT + o];
        float w2 = wt[(i * GRID_N + 2) * OUT + o];
        float w3 = wt[(i * GRID_N + 3) * OUT + o];
        float w4 = wt[(i * GRID_N + 4) * OUT + o];
#pragma unroll
        for (int j = 0; j < BPT; j++) {
            float xv = xn[bg * BPT + j][i];   // LDS broadcast (uniform across lanes)
            acc[j] += w0 * __builtin_amdgcn_exp2f(K * fabsf(xv + 1.0f));
            acc[j] += w1 * __builtin_amdgcn_exp2f(K * fabsf(xv + 0.5f));
            acc[j] += w2 * __builtin_amdgcn_exp2f(K * fabsf(xv));
            acc[j] += w3 * __builtin_amdgcn_exp2f(K * fabsf(xv - 0.5f));
            acc[j] += w4 * __builtin_amdgcn_exp2f(K * fabsf(xv - 1.0f));
        }
    }

#pragma unroll
    for (int j = 0; j < BPT; j++) {
        int b = b0 + bg * BPT + j;
        float z = acc[j];
        if (ACT == 0) {
            z = fmaxf(z, 0.0f);
        } else {
            float t = __builtin_amdgcn_exp2f(-LOG2E * z);
            z = 1.0f / (1.0f + t);
        }
        out[b * OUT + o] = z;
    }
}

extern "C" void kernel_launch(void* const* d_in, const int* in_sizes, int n_in,
                              void* d_out, int out_size, void* d_ws, size_t ws_size,
                              hipStream_t stream) {
    const float* x  = (const float*)d_in[0];
    const float* w1 = (const float*)d_in[1];
    const float* s1 = (const float*)d_in[2];
    const float* w2 = (const float*)d_in[3];
    const float* s2 = (const float*)d_in[4];
    const float* w3 = (const float*)d_in[5];
    const float* s3 = (const float*)d_in[6];
    float* out = (float*)d_out;

    float* ws  = (float*)d_ws;
    float* h1  = ws;                    // 2048*256 = 524288
    float* h2  = h1  + 524288;          // 2048*128 = 262144
    float* w1t = h2  + 262144;          // 128*5*256 = 163840
    float* s1t = w1t + 163840;          // 128*256   = 32768
    float* w2t = s1t + 32768;           // 256*5*128 = 163840
    float* s2t = w2t + 163840;          // 256*128   = 32768
    float* w3t = s2t + 32768;           // 128*5*64  = 40960
    float* s3t = w3t + 40960;           // 128*64    = 8192

    // transpose + fold -log2e into scaler
    prep_w<<<640, 256, 0, stream>>>(w1, w1t, 256, 128);
    prep_s<<<128, 256, 0, stream>>>(s1, s1t, 256, 128);
    prep_w<<<640, 256, 0, stream>>>(w2, w2t, 128, 256);
    prep_s<<<128, 256, 0, stream>>>(s2, s2t, 128, 256);
    prep_w<<<160, 256, 0, stream>>>(w3, w3t, 64, 128);
    prep_s<<< 32, 256, 0, stream>>>(s3, s3t, 64, 128);

    // layers (B=2048, BT=4 -> 512 blocks)
    kan_layer<128, 256, 0, 4><<<512, 256, 0, stream>>>(x,  w1t, s1t, h1);
    kan_layer<256, 128, 0, 4><<<512, 256, 0, stream>>>(h1, w2t, s2t, h2);
    kan_layer<128,  64, 1, 4><<<512, 256, 0, stream>>>(h2, w3t, s3t, out);
}

// Round 2
// 111.488 us; speedup vs baseline: 1.4677x; 1.4677x over previous
//
#include <hip/hip_runtime.h>
#include <math.h>

#define GRID_N 5
#define LOG2E 1.4426950408889634f

// Build per-(i,o) bin tables:
//   K = -s*log2e
//   A[k] = sum_{g_idx < k} w_g * 2^{-K*g}   (grid points <= xn when bin=k)
//   B[k] = sum_{g_idx >= k} w_g * 2^{+K*g}  (grid points  > xn)
// stored as T[i][k][o][2] = {A,B};  Kt[i][o] = K
__global__ void prep_tab(const float* __restrict__ w, const float* __restrict__ s,
                         float* __restrict__ T, float* __restrict__ Kt, int O, int I) {
    int idx = blockIdx.x * 256 + threadIdx.x;
    if (idx >= O * I) return;
    int o = idx / I, i = idx % I;               // w,s are [O][I(][G)]
    float K = -s[idx] * LOG2E;
    const float gv[5] = {-1.f, -0.5f, 0.f, 0.5f, 1.f};
    float A[6], B[6];
    A[0] = 0.f; B[5] = 0.f;
#pragma unroll
    for (int g = 0; g < 5; g++) {
        float wv = w[idx * GRID_N + g];
        A[g + 1] = A[g] + wv * __builtin_amdgcn_exp2f(-K * gv[g]);
    }
#pragma unroll
    for (int g = 4; g >= 0; g--) {
        float wv = w[idx * GRID_N + g];
        B[g] = B[g + 1] + wv * __builtin_amdgcn_exp2f(K * gv[g]);
    }
#pragma unroll
    for (int k = 0; k < 6; k++) {
        T[((i * 6 + k) * O + o) * 2 + 0] = A[k];
        T[((i * 6 + k) * O + o) * 2 + 1] = B[k];
    }
    Kt[i * O + o] = K;
}

// out[b,o] = act( sum_i  A[i,bin(b,i),o]*2^{K*xn} + B[i,bin(b,i),o]*2^{-K*xn} )
// ACT: 0 = relu, 1 = sigmoid
template<int IN, int OUT, int ACT, int BT, int NT>
__global__ __launch_bounds__(NT) void kan_layer(
    const float* __restrict__ x,     // [B][IN] (pre-tanh)
    const float* __restrict__ T,     // [IN][6][OUT][2]
    const float* __restrict__ Kt,    // [IN][OUT]
    float* __restrict__ out)         // [B][OUT]
{
    constexpr int WB  = NT / OUT;    // b-groups among threads
    constexpr int BPT = BT / WB;     // b rows per thread
    __shared__ float xn[BT][IN];
    __shared__ int   bn[BT][IN];     // bin pre-scaled to element offset k*OUT*2

    const int tid = threadIdx.x;
    const int b0  = blockIdx.x * BT;

    // stage: tanh + bin index (bin depends only on (b,i), not o)
    for (int e = tid; e < BT * IN; e += NT) {
        int bb = e / IN, ii = e % IN;
        float v  = x[(b0 + bb) * IN + ii];
        float ex = __builtin_amdgcn_exp2f(2.0f * LOG2E * v);
        float xv = 1.0f - 2.0f / (ex + 1.0f);           // tanh, NaN-safe
        int k = (int)((xv + 1.0f) * 2.0f) + 1;          // #{g <= xv}, xv in [-1,1]
        k = k > 5 ? 5 : k;
        xn[bb][ii] = xv;
        bn[bb][ii] = k * (OUT * 2);
    }
    __syncthreads();

    const int o  = tid % OUT;
    const int bg = tid / OUT;
    const float* To = T + o * 2;

    float acc[BPT];
#pragma unroll
    for (int j = 0; j < BPT; j++) acc[j] = 0.f;

#pragma unroll 4
    for (int i = 0; i < IN; i++) {
        float K   = Kt[i * OUT + o];
        int  base = i * (6 * OUT * 2);
#pragma unroll
        for (int j = 0; j < BPT; j++) {
            float xv  = xn[bg * BPT + j][i];            // LDS broadcast
            int   off = bn[bg * BPT + j][i];            // LDS broadcast
            float2 ab = *reinterpret_cast<const float2*>(To + base + off);
            float t = K * xv;
            acc[j] += ab.x * __builtin_amdgcn_exp2f(t)
                    + ab.y * __builtin_amdgcn_exp2f(-t);
        }
    }

#pragma unroll
    for (int j = 0; j < BPT; j++) {
        int b = b0 + bg * BPT + j;
        float z = acc[j];
        if (ACT == 0) {
            z = fmaxf(z, 0.f);
        } else {
            float e2 = __builtin_amdgcn_exp2f(-LOG2E * z);
            z = 1.0f / (1.0f + e2);
        }
        out[b * OUT + o] = z;
    }
}

extern "C" void kernel_launch(void* const* d_in, const int* in_sizes, int n_in,
                              void* d_out, int out_size, void* d_ws, size_t ws_size,
                              hipStream_t stream) {
    const float* x  = (const float*)d_in[0];
    const float* w1 = (const float*)d_in[1];
    const float* s1 = (const float*)d_in[2];
    const float* w2 = (const float*)d_in[3];
    const float* s2 = (const float*)d_in[4];
    const float* w3 = (const float*)d_in[5];
    const float* s3 = (const float*)d_in[6];
    float* out = (float*)d_out;

    float* ws  = (float*)d_ws;
    float* h1  = ws;                    // 2048*256            = 524288
    float* h2  = h1  + 524288;          // 2048*128            = 262144
    float* T1  = h2  + 262144;          // 128*6*256*2         = 393216
    float* K1  = T1  + 393216;          // 128*256             = 32768
    float* T2  = K1  + 32768;           // 256*6*128*2         = 393216
    float* K2  = T2  + 393216;          // 256*128             = 32768
    float* T3  = K2  + 32768;           // 128*6*64*2          = 98304
    float* K3  = T3  + 98304;           // 128*64              = 8192

    prep_tab<<<128, 256, 0, stream>>>(w1, s1, T1, K1, 256, 128);
    prep_tab<<<128, 256, 0, stream>>>(w2, s2, T2, K2, 128, 256);
    prep_tab<<< 32, 256, 0, stream>>>(w3, s3, T3, K3,  64, 128);

    // L1: 1024 blocks (4 blk/CU, 16 waves/CU), BPT=2
    kan_layer<128, 256, 0, 2, 256><<<1024, 256, 0, stream>>>(x,  T1, K1, h1);
    // L2: 512 blocks (2 blk/CU, 8 waves/CU), BPT=2  — occupancy A/B vs L1
    kan_layer<256, 128, 0, 4, 256><<< 512, 256, 0, stream>>>(h1, T2, K2, h2);
    // L3: small
    kan_layer<128,  64, 1, 4, 256><<< 512, 256, 0, stream>>>(h2, T3, K3, out);
}

// Round 3
// 109.683 us; speedup vs baseline: 1.4919x; 1.0165x over previous
//
#include <hip/hip_runtime.h>
#include <math.h>

#define GRID_N 5
#define LOG2E 1.4426950408889634f
#define EXP2F __builtin_amdgcn_exp2f

// Build per-(i,o) bin tables:
//   K = -s*log2e
//   A[k] = sum_{g_idx < k} w_g * 2^{-K*g}   (grid points <= xn when bin=k)
//   B[k] = sum_{g_idx >= k} w_g * 2^{+K*g}  (grid points  > xn)
// stored as T[i][k][o][2] = {A,B};  Kt[i][o] = K
__global__ void prep_tab(const float* __restrict__ w, const float* __restrict__ s,
                         float* __restrict__ T, float* __restrict__ Kt, int O, int I) {
    int idx = blockIdx.x * 256 + threadIdx.x;
    if (idx >= O * I) return;
    int o = idx / I, i = idx % I;               // w,s are [O][I(][G)]
    float K = -s[idx] * LOG2E;
    const float gv[5] = {-1.f, -0.5f, 0.f, 0.5f, 1.f};
    float A[6], B[6];
    A[0] = 0.f; B[5] = 0.f;
#pragma unroll
    for (int g = 0; g < 5; g++) {
        float wv = w[idx * GRID_N + g];
        A[g + 1] = A[g] + wv * EXP2F(-K * gv[g]);
    }
#pragma unroll
    for (int g = 4; g >= 0; g--) {
        float wv = w[idx * GRID_N + g];
        B[g] = B[g + 1] + wv * EXP2F(K * gv[g]);
    }
#pragma unroll
    for (int k = 0; k < 6; k++) {
        T[((i * 6 + k) * O + o) * 2 + 0] = A[k];
        T[((i * 6 + k) * O + o) * 2 + 1] = B[k];
    }
    Kt[i * O + o] = K;
}

// out[b,o] = act( sum_i A[i,bin,o]*2^{K*xn} + B[i,bin,o]*2^{-K*xn} ),  xn = tanh(xin)
// Wave-level org: each wave owns (b-group of BPT rows) x (64 consecutive o's).
// xn/bin held lane-private (lane l holds i = c*64+l), broadcast via v_readlane.
// NO LDS in the kernel at all.
template<int IN, int OUT, int ACT, int BPT>
__global__ __launch_bounds__(256) void kan_layer(
    const float* __restrict__ xin,   // [B][IN] raw (pre-tanh)
    const float* __restrict__ T,     // [IN][6][OUT][2]
    const float* __restrict__ Kt,    // [IN][OUT]
    float* __restrict__ out)         // [B][OUT]
{
    constexpr int OCH = OUT / 64;    // o-chunks of 64
    constexpr int CH  = IN / 64;     // i-chunks of 64
    const int lane = threadIdx.x & 63;
    const int wid  = (blockIdx.x << 2) | (threadIdx.x >> 6);  // global wave id
    const int oc   = wid % OCH;
    const int bg   = wid / OCH;
    const int o    = (oc << 6) | lane;
    const int b0   = bg * BPT;

    // per-lane tanh + bin for this wave's BPT rows (lane l -> i = c*64+l)
    float xv[BPT][CH];
    int   bo[BPT][CH];               // bin scaled to byte offset bin*OUT*8
#pragma unroll
    for (int j = 0; j < BPT; j++)
#pragma unroll
        for (int c = 0; c < CH; c++) {
            float v  = xin[(b0 + j) * IN + (c << 6) + lane];
            float ex = EXP2F(2.0f * LOG2E * v);
            float t  = 1.0f - 2.0f / (ex + 1.0f);     // tanh, NaN-safe
            xv[j][c] = t;
            int k = (int)((t + 1.0f) * 2.0f) + 1;     // #{g <= t}, t in [-1,1]
            bo[j][c] = (k > 5 ? 5 : k) * (OUT * 8);
        }

    float acc[BPT];
#pragma unroll
    for (int j = 0; j < BPT; j++) acc[j] = 0.f;

    const char*  Tb = (const char*)T;
    const float* Kp = Kt + o;

#pragma unroll
    for (int c = 0; c < CH; c++) {
#pragma unroll 8
        for (int l = 0; l < 64; l++) {
            const int i = (c << 6) + l;
            float K = Kp[i * OUT];                    // coalesced VGPR load
            const char* Ti = Tb + (size_t)i * (6 * OUT * 8) + (o << 3);
#pragma unroll
            for (int j = 0; j < BPT; j++) {
                float xs = __int_as_float(__builtin_amdgcn_readlane(__float_as_int(xv[j][c]), l));
                int   bs = __builtin_amdgcn_readlane(bo[j][c], l);
                const float2 ab = *(const float2*)(Ti + bs);
                float t = K * xs;
                acc[j] += ab.x * EXP2F(t) + ab.y * EXP2F(-t);
            }
        }
    }

#pragma unroll
    for (int j = 0; j < BPT; j++) {
        float z = acc[j];
        if (ACT == 0) {
            z = fmaxf(z, 0.f);
        } else {
            z = 1.0f / (1.0f + EXP2F(-LOG2E * z));
        }
        out[(b0 + j) * OUT + o] = z;
    }
}

extern "C" void kernel_launch(void* const* d_in, const int* in_sizes, int n_in,
                              void* d_out, int out_size, void* d_ws, size_t ws_size,
                              hipStream_t stream) {
    const float* x  = (const float*)d_in[0];
    const float* w1 = (const float*)d_in[1];
    const float* s1 = (const float*)d_in[2];
    const float* w2 = (const float*)d_in[3];
    const float* s2 = (const float*)d_in[4];
    const float* w3 = (const float*)d_in[5];
    const float* s3 = (const float*)d_in[6];
    float* out = (float*)d_out;

    float* ws  = (float*)d_ws;
    float* h1  = ws;                    // 2048*256            = 524288
    float* h2  = h1  + 524288;          // 2048*128            = 262144
    float* T1  = h2  + 262144;          // 128*6*256*2         = 393216
    float* K1  = T1  + 393216;          // 128*256             = 32768
    float* T2  = K1  + 32768;           // 256*6*128*2         = 393216
    float* K2  = T2  + 393216;          // 256*128             = 32768
    float* T3  = K2  + 32768;           // 128*6*64*2          = 98304
    float* K3  = T3  + 98304;           // 128*64              = 8192

    prep_tab<<<128, 256, 0, stream>>>(w1, s1, T1, K1, 256, 128);
    prep_tab<<<128, 256, 0, stream>>>(w2, s2, T2, K2, 128, 256);
    prep_tab<<< 32, 256, 0, stream>>>(w3, s3, T3, K3,  64, 128);

    // L1: OCH=4, BPT=2 -> waves = 1024*4 -> 1024 blocks (16 waves/CU)
    kan_layer<128, 256, 0, 2><<<1024, 256, 0, stream>>>(x,  T1, K1, h1);
    // L2: OCH=2, BPT=1 -> waves = 2048*2 -> 1024 blocks (16 waves/CU)
    kan_layer<256, 128, 0, 1><<<1024, 256, 0, stream>>>(h1, T2, K2, h2);
    // L3: OCH=1, BPT=1 -> waves = 2048   ->  512 blocks
    kan_layer<128,  64, 1, 1><<< 512, 256, 0, stream>>>(h2, T3, K3, out);
}